// Round 4
// baseline (678.931 us; speedup 1.0000x reference)
//
#include <hip/hip_runtime.h>

// CSR-binned gather projector.
// R1: LDS-atomic scatter -> 645us (ds_add_f32 ~2.8cy/lane floor).
// R2/R3: gather w/ per-block rescan -> 267us, invariant to inner-loop work =>
//        bottleneck is the 20x-redundant scan + barrier scaffolding (95% reject).
// R4: bin atoms into per-(b,tile) CSR lists once (count/scan/fill), then render
//     each tile from its packed list: no barriers in hot loop, wave-uniform
//     prefetched loads, 4 independent native v_exp_f32 chains.

#define S 128
#define TS 16
#define TPS 8
#define NTILES 64            // tiles per image
#define RAD 6.5f             // truncation: err ~ 8*exp(-6.5^2/4.5) ~ 7e-4 << 0.235
#define BLOCK 256
#define NSPLIT2 4            // render blocks per (b,tile) segment (load balance)

#if __has_builtin(__builtin_amdgcn_exp2f)
#define FAST_EXP2(x) __builtin_amdgcn_exp2f(x)
#else
#define FAST_EXP2(x) exp2f(x)
#endif
#if __has_builtin(__builtin_amdgcn_rcpf)
#define FAST_RCP(x) __builtin_amdgcn_rcpf(x)
#else
#define FAST_RCP(x) (1.0f / (x))
#endif

__device__ __forceinline__ bool atom_bbox(float x, float y,
                                          int& tx0, int& tx1, int& ty0, int& ty1) {
    float cx = x + 63.5f, cy = y + 63.5f;
    int w0 = max(0,     (int)ceilf (cx - RAD));
    int w1 = min(S - 1, (int)floorf(cx + RAD));
    int h0 = max(0,     (int)ceilf (cy - RAD));
    int h1 = min(S - 1, (int)floorf(cy + RAD));
    if (w0 > w1 || h0 > h1) return false;
    tx0 = w0 >> 4; tx1 = w1 >> 4; ty0 = h0 >> 4; ty1 = h1 >> 4;
    return true;
}

__global__ __launch_bounds__(BLOCK) void k_count(const float* __restrict__ mol,
                                                 int* __restrict__ cnt, int B, int A) {
    int idx = blockIdx.x * BLOCK + threadIdx.x;
    if (idx >= B * A) return;
    int b = idx / A;
    float x = mol[(size_t)idx * 3 + 0];
    float y = mol[(size_t)idx * 3 + 1];
    int tx0, tx1, ty0, ty1;
    if (!atom_bbox(x, y, tx0, tx1, ty0, ty1)) return;
    for (int ty = ty0; ty <= ty1; ++ty)
        for (int tx = tx0; tx <= tx1; ++tx)
            atomicAdd(&cnt[b * NTILES + ty * TPS + tx], 1);
}

__global__ __launch_bounds__(1024) void k_scan(const int* __restrict__ cnt,
                                               int* __restrict__ cursor,
                                               int* __restrict__ segstart,
                                               int* __restrict__ segend, int NT) {
    __shared__ int buf[2][1024];
    int t = threadIdx.x;
    int v = (t < NT) ? cnt[t] : 0;
    buf[0][t] = v;
    __syncthreads();
    int src = 0;
    for (int d = 1; d < 1024; d <<= 1) {
        int xv = buf[src][t];
        if (t >= d) xv += buf[src][t - d];
        buf[src ^ 1][t] = xv;
        __syncthreads();
        src ^= 1;
    }
    if (t < NT) {
        int inc = buf[src][t];       // inclusive sum
        cursor[t]   = inc - v;       // exclusive start (fill cursor)
        segstart[t] = inc - v;
        segend[t]   = inc;
    }
}

__global__ __launch_bounds__(BLOCK) void k_fill(const float* __restrict__ mol,
                                                const float* __restrict__ stds,
                                                const float* __restrict__ dens,
                                                int* __restrict__ cursor,
                                                float4* __restrict__ ent,
                                                int B, int A, int cap) {
    int idx = blockIdx.x * BLOCK + threadIdx.x;
    if (idx >= B * A) return;
    int b = idx / A, a = idx - b * A;
    float x = mol[(size_t)idx * 3 + 0];
    float y = mol[(size_t)idx * 3 + 1];
    int tx0, tx1, ty0, ty1;
    if (!atom_bbox(x, y, tx0, tx1, ty0, ty1)) return;
    float sd   = stds[a];
    float var  = sd * sd;
    float rinv = FAST_RCP(var);
    float k    = -0.72134752044448f * rinv;                          // -0.5*log2e/var
    float c2   = __log2f(dens[a] * 0.15915494309189535f * rinv);     // log2(coef)
    float4 e = make_float4(x, y, k, c2);
    for (int ty = ty0; ty <= ty1; ++ty)
        for (int tx = tx0; tx <= tx1; ++tx) {
            int pos = atomicAdd(&cursor[b * NTILES + ty * TPS + tx], 1);
            if (pos < cap) ent[pos] = e;
        }
}

__global__ __launch_bounds__(BLOCK) void k_render(const float4* __restrict__ ent,
                                                  const int* __restrict__ segstart,
                                                  const int* __restrict__ segend,
                                                  float* __restrict__ out, int cap) {
    __shared__ float wtile[4 * 256];

    const int tile  = blockIdx.x;          // 0..63
    const int split = blockIdx.y;          // 0..NSPLIT2-1
    const int b     = blockIdx.z;
    const int tid   = threadIdx.x;
    const int lane  = tid & 63;
    const int wav   = tid >> 6;

    const int tx0 = (tile & 7) * TS, ty0 = (tile >> 3) * TS;
    const int col = lane & 15, row0 = lane >> 4;
    const float pxf = (float)(tx0 + col)  - 63.5f;
    const float py0 = (float)(ty0 + row0) - 63.5f;

    const int tileid = b * NTILES + tile;
    const int st = segstart[tileid];
    const int en = min(segend[tileid], cap);
    const int len = max(0, en - st);
    const int per = (len + NSPLIT2 - 1) / NSPLIT2;
    const int s0 = st + split * per;
    const int s1 = min(s0 + per, en);

    float a0 = 0.0f, a1 = 0.0f, a2 = 0.0f, a3 = 0.0f;

    if (s1 > s0) {
        const int last = s1 - 1;
        int i = s0 + wav;                       // wave-uniform index
        float4 cur = ent[min(i, last)];         // 2-deep register prefetch
        float4 nxt = ent[min(i + 4, last)];
        for (; i < s1; i += 4) {
            float4 aft = ent[min(i + 8, last)];
            float dx  = pxf - cur.x;
            float dx2 = dx * dx;
            float dy0 = py0          - cur.y;
            float dy1 = py0 +  4.0f  - cur.y;
            float dy2 = py0 +  8.0f  - cur.y;
            float dy3 = py0 + 12.0f  - cur.y;
            a0 += FAST_EXP2(fmaf(fmaf(dy0, dy0, dx2), cur.z, cur.w));
            a1 += FAST_EXP2(fmaf(fmaf(dy1, dy1, dx2), cur.z, cur.w));
            a2 += FAST_EXP2(fmaf(fmaf(dy2, dy2, dx2), cur.z, cur.w));
            a3 += FAST_EXP2(fmaf(fmaf(dy3, dy3, dx2), cur.z, cur.w));
            cur = nxt; nxt = aft;
        }
    }

    // cross-wave reduce: wave w's acc_j (pixel p = 64j + lane) -> wtile[w*256 + p]
    wtile[wav * 256 +   0 + lane] = a0;
    wtile[wav * 256 +  64 + lane] = a1;
    wtile[wav * 256 + 128 + lane] = a2;
    wtile[wav * 256 + 192 + lane] = a3;
    __syncthreads();

    float v = wtile[tid] + wtile[256 + tid] + wtile[512 + tid] + wtile[768 + tid];
    int row = tid >> 4, c = tid & 15;
    atomicAdd(&out[((size_t)b * S + (ty0 + row)) * S + (tx0 + c)], v);
}

extern "C" void kernel_launch(void* const* d_in, const int* in_sizes, int n_in,
                              void* d_out, int out_size, void* d_ws, size_t ws_size,
                              hipStream_t stream) {
    const float* mol  = (const float*)d_in[0];
    const float* stds = (const float*)d_in[1];
    const float* dens = (const float*)d_in[2];
    float* out = (float*)d_out;

    const int A = in_sizes[1];             // 20000
    const int B = in_sizes[0] / (A * 3);   // 16
    const int NT = B * NTILES;             // 1024

    char* ws = (char*)d_ws;
    int* cnt      = (int*)(ws);            // 4 KB
    int* cursor   = (int*)(ws + 4096);     // 4 KB
    int* segstart = (int*)(ws + 8192);     // 4 KB
    int* segend   = (int*)(ws + 12288);    // 4 KB
    float4* ent   = (float4*)(ws + 16384); // ~17 MB needed (avg), <=20.5 MB worst

    long cap64 = ((long)ws_size - 16384) / 16;
    int cap = (cap64 > 0x7fffffffL) ? 0x7fffffff : (cap64 < 0 ? 0 : (int)cap64);

    hipMemsetAsync(cnt, 0, NT * sizeof(int), stream);
    hipMemsetAsync(d_out, 0, (size_t)out_size * sizeof(float), stream);

    const int n  = B * A;
    const int nb = (n + BLOCK - 1) / BLOCK;
    k_count <<<nb, BLOCK, 0, stream>>>(mol, cnt, B, A);
    k_scan  <<<1, 1024, 0, stream>>>(cnt, cursor, segstart, segend, NT);
    k_fill  <<<nb, BLOCK, 0, stream>>>(mol, stds, dens, cursor, ent, B, A, cap);
    k_render<<<dim3(NTILES, NSPLIT2, B), dim3(BLOCK), 0, stream>>>(ent, segstart, segend, out, cap);
}

// Round 5
// 278.555 us; speedup vs baseline: 2.4373x; 2.4373x over previous
//
#include <hip/hip_runtime.h>

// CSR-binned gather projector, contention-free binning.
// R1: LDS-atomic scatter into private image -> 645us (ds atomic pipe floor).
// R2/R3: per-block rescan gather -> 267us (20x redundant scan + barriers).
// R4: CSR via global atomics on 1024 contiguous cursors -> 679us; k_count/k_fill
//     at VALUBusy 0.4% = same-cache-line atomic serialization at L2.
// R5: per-block LDS histograms + 2-level scan (radix-binning style). No global
//     atomic sees more than ~4 ops/address. Render unchanged (was never top-5).

#define S 128
#define TS 16
#define TPS 8
#define NTILES 64            // tiles per image (8x8)
#define NBINS 1024           // B * NTILES
#define RAD 6.5f             // truncation: err ~ 8*exp(-6.5^2/4.5) ~ 7e-4 << 0.235
#define BLOCK 256
#define NBH 256              // histogram/fill blocks
#define NSPLIT2 4            // render blocks per (b,tile) segment

#if __has_builtin(__builtin_amdgcn_exp2f)
#define FAST_EXP2(x) __builtin_amdgcn_exp2f(x)
#else
#define FAST_EXP2(x) exp2f(x)
#endif
#if __has_builtin(__builtin_amdgcn_rcpf)
#define FAST_RCP(x) __builtin_amdgcn_rcpf(x)
#else
#define FAST_RCP(x) (1.0f / (x))
#endif

__device__ __forceinline__ bool atom_bbox(float x, float y,
                                          int& tx0, int& tx1, int& ty0, int& ty1) {
    float cx = x + 63.5f, cy = y + 63.5f;
    int w0 = max(0,     (int)ceilf (cx - RAD));
    int w1 = min(S - 1, (int)floorf(cx + RAD));
    int h0 = max(0,     (int)ceilf (cy - RAD));
    int h1 = min(S - 1, (int)floorf(cy + RAD));
    if (w0 > w1 || h0 > h1) return false;
    tx0 = w0 >> 4; tx1 = w1 >> 4; ty0 = h0 >> 4; ty1 = h1 >> 4;
    return true;
}

// hist layout: hist[bin * NBH + blk]  (coalesced for the per-bin scan)
__global__ __launch_bounds__(BLOCK) void k_hist(const float* __restrict__ mol,
                                                int* __restrict__ hist, int B, int A) {
    __shared__ int h[NBINS];
    const int tid = threadIdx.x, blk = blockIdx.x;
    for (int i = tid; i < NBINS; i += BLOCK) h[i] = 0;
    __syncthreads();

    const int n = B * A;
    const int per = (n + NBH - 1) / NBH;
    const int i0 = blk * per;
    const int i1 = min(i0 + per, n);
    for (int idx = i0 + tid; idx < i1; idx += BLOCK) {
        int b = idx / A;
        float x = mol[(size_t)idx * 3 + 0];
        float y = mol[(size_t)idx * 3 + 1];
        int tx0, tx1, ty0, ty1;
        if (!atom_bbox(x, y, tx0, tx1, ty0, ty1)) continue;
        for (int ty = ty0; ty <= ty1; ++ty)
            for (int tx = tx0; tx <= tx1; ++tx)
                atomicAdd(&h[b * NTILES + ty * TPS + tx], 1);
    }
    __syncthreads();
    for (int i = tid; i < NBINS; i += BLOCK) hist[i * NBH + blk] = h[i];
}

// per-bin exclusive scan over the NBH=256 block counts (one wave per bin)
__global__ __launch_bounds__(64) void k_scan_a(int* __restrict__ hist,
                                               int* __restrict__ total) {
    const int bin = blockIdx.x, lane = threadIdx.x;
    const int base = bin * NBH + lane * 4;
    int v0 = hist[base], v1 = hist[base + 1], v2 = hist[base + 2], v3 = hist[base + 3];
    int s = v0 + v1 + v2 + v3;
    int inc = s;
    for (int d = 1; d < 64; d <<= 1) {
        int t = __shfl_up(inc, d);
        if (lane >= d) inc += t;
    }
    int excl = inc - s;
    hist[base]     = excl;
    hist[base + 1] = excl + v0;
    hist[base + 2] = excl + v0 + v1;
    hist[base + 3] = excl + v0 + v1 + v2;
    if (lane == 63) total[bin] = inc;
}

// global exclusive scan over the 1024 bin totals
__global__ __launch_bounds__(1024) void k_scan_b(const int* __restrict__ total,
                                                 int* __restrict__ segstart,
                                                 int* __restrict__ segend) {
    __shared__ int buf[2][NBINS];
    int t = threadIdx.x;
    int v = total[t];
    buf[0][t] = v;
    __syncthreads();
    int src = 0;
    for (int d = 1; d < NBINS; d <<= 1) {
        int xv = buf[src][t];
        if (t >= d) xv += buf[src][t - d];
        buf[src ^ 1][t] = xv;
        __syncthreads();
        src ^= 1;
    }
    int inc = buf[src][t];
    segstart[t] = inc - v;
    segend[t]   = inc;
}

__global__ __launch_bounds__(BLOCK) void k_fill(const float* __restrict__ mol,
                                                const float* __restrict__ stds,
                                                const float* __restrict__ dens,
                                                const int* __restrict__ hist,
                                                const int* __restrict__ segstart,
                                                float4* __restrict__ ent,
                                                int B, int A, int cap) {
    __shared__ int cur[NBINS];
    const int tid = threadIdx.x, blk = blockIdx.x;
    for (int i = tid; i < NBINS; i += BLOCK)
        cur[i] = segstart[i] + hist[i * NBH + blk];
    __syncthreads();

    const int n = B * A;
    const int per = (n + NBH - 1) / NBH;
    const int i0 = blk * per;
    const int i1 = min(i0 + per, n);
    for (int idx = i0 + tid; idx < i1; idx += BLOCK) {
        int b = idx / A, a = idx - b * A;
        float x = mol[(size_t)idx * 3 + 0];
        float y = mol[(size_t)idx * 3 + 1];
        int tx0, tx1, ty0, ty1;
        if (!atom_bbox(x, y, tx0, tx1, ty0, ty1)) continue;
        float sd   = stds[a];
        float var  = sd * sd;
        float rinv = FAST_RCP(var);
        float k    = -0.72134752044448f * rinv;                      // -0.5*log2e/var
        float c2   = __log2f(dens[a] * 0.15915494309189535f * rinv); // log2(coef)
        float4 e = make_float4(x, y, k, c2);
        for (int ty = ty0; ty <= ty1; ++ty)
            for (int tx = tx0; tx <= tx1; ++tx) {
                int pos = atomicAdd(&cur[b * NTILES + ty * TPS + tx], 1);
                if (pos < cap) ent[pos] = e;
            }
    }
}

__global__ __launch_bounds__(BLOCK) void k_render(const float4* __restrict__ ent,
                                                  const int* __restrict__ segstart,
                                                  const int* __restrict__ segend,
                                                  float* __restrict__ out, int cap) {
    __shared__ float wtile[4 * 256];

    const int tile  = blockIdx.x;          // 0..63
    const int split = blockIdx.y;          // 0..NSPLIT2-1
    const int b     = blockIdx.z;
    const int tid   = threadIdx.x;
    const int lane  = tid & 63;
    const int wav   = tid >> 6;

    const int tx0 = (tile & 7) * TS, ty0 = (tile >> 3) * TS;
    const int col = lane & 15, row0 = lane >> 4;
    const float pxf = (float)(tx0 + col)  - 63.5f;
    const float py0 = (float)(ty0 + row0) - 63.5f;

    const int tileid = b * NTILES + tile;
    const int st = segstart[tileid];
    const int en = min(segend[tileid], cap);
    const int len = max(0, en - st);
    const int per = (len + NSPLIT2 - 1) / NSPLIT2;
    const int s0 = st + split * per;
    const int s1 = min(s0 + per, en);

    float a0 = 0.0f, a1 = 0.0f, a2 = 0.0f, a3 = 0.0f;

    if (s1 > s0) {
        const int last = s1 - 1;
        int i = s0 + wav;                       // wave-uniform index
        float4 cur = ent[min(i, last)];         // 2-deep register prefetch
        float4 nxt = ent[min(i + 4, last)];
        for (; i < s1; i += 4) {
            float4 aft = ent[min(i + 8, last)];
            float dx  = pxf - cur.x;
            float dx2 = dx * dx;
            float dy0 = py0          - cur.y;
            float dy1 = py0 +  4.0f  - cur.y;
            float dy2 = py0 +  8.0f  - cur.y;
            float dy3 = py0 + 12.0f  - cur.y;
            a0 += FAST_EXP2(fmaf(fmaf(dy0, dy0, dx2), cur.z, cur.w));
            a1 += FAST_EXP2(fmaf(fmaf(dy1, dy1, dx2), cur.z, cur.w));
            a2 += FAST_EXP2(fmaf(fmaf(dy2, dy2, dx2), cur.z, cur.w));
            a3 += FAST_EXP2(fmaf(fmaf(dy3, dy3, dx2), cur.z, cur.w));
            cur = nxt; nxt = aft;
        }
    }

    wtile[wav * 256 +   0 + lane] = a0;
    wtile[wav * 256 +  64 + lane] = a1;
    wtile[wav * 256 + 128 + lane] = a2;
    wtile[wav * 256 + 192 + lane] = a3;
    __syncthreads();

    float v = wtile[tid] + wtile[256 + tid] + wtile[512 + tid] + wtile[768 + tid];
    int row = tid >> 4, c = tid & 15;
    atomicAdd(&out[((size_t)b * S + (ty0 + row)) * S + (tx0 + c)], v);
}

extern "C" void kernel_launch(void* const* d_in, const int* in_sizes, int n_in,
                              void* d_out, int out_size, void* d_ws, size_t ws_size,
                              hipStream_t stream) {
    const float* mol  = (const float*)d_in[0];
    const float* stds = (const float*)d_in[1];
    const float* dens = (const float*)d_in[2];
    float* out = (float*)d_out;

    const int A = in_sizes[1];             // 20000
    const int B = in_sizes[0] / (A * 3);   // 16

    char* ws = (char*)d_ws;
    int* total    = (int*)(ws);                        // 4 KB
    int* segstart = (int*)(ws + 4096);                 // 4 KB
    int* segend   = (int*)(ws + 8192);                 // 4 KB
    int* hist     = (int*)(ws + 16384);                // NBINS*NBH*4 = 1 MB
    const size_t ent_off = 16384 + (size_t)NBINS * NBH * 4;
    float4* ent   = (float4*)(ws + ent_off);           // ~17 MB avg, <=20.5 MB worst

    long cap64 = ((long)ws_size - (long)ent_off) / 16;
    int cap = (cap64 > 0x7fffffffL) ? 0x7fffffff : (cap64 < 0 ? 0 : (int)cap64);

    hipMemsetAsync(d_out, 0, (size_t)out_size * sizeof(float), stream);

    k_hist  <<<NBH, BLOCK, 0, stream>>>(mol, hist, B, A);
    k_scan_a<<<NBINS, 64, 0, stream>>>(hist, total);
    k_scan_b<<<1, 1024, 0, stream>>>(total, segstart, segend);
    k_fill  <<<NBH, BLOCK, 0, stream>>>(mol, stds, dens, hist, segstart, ent, B, A, cap);
    k_render<<<dim3(NTILES, NSPLIT2, B), dim3(BLOCK), 0, stream>>>(ent, segstart, segend, out, cap);
}

// Round 6
// 114.809 us; speedup vs baseline: 5.9136x; 2.4263x over previous
//
#include <hip/hip_runtime.h>

// Dense separable projector on f16 matrix cores.
// img_b = Gy_b^T (128 x K) . Gx_b (K x 128), K = A = 20000.
// History: R1 LDS-atomic scatter 645us; R2/R3 fused gather 267us (256M exps,
// latency-starved); R4 global-atomic CSR 679us (same-cache-line atomic wall);
// R5 binned gather 278us (render alone 202us -> the non-separable gather's
// 256M-exp floor). Separable form: 82M exps + 10.5 GFLOP of f16 MFMA.
// Block = (K-split of 625 atoms, batch); per 32-atom chunk stage Gx/Gy*coef
// as f16 [pos][k] in LDS, one 16x16x32 MFMA per output tile per chunk.
// Epilogue: distinct-address global atomics merge the 32 K-splits.

#define S 128
#define KB 32            // atoms per chunk = MFMA K
#define KSPLIT 32        // K-splits per batch -> 512 blocks, 2/CU
#define BLOCK 256
#define LDST 40          // f16 per LDS row (80 B): rows 16B-aligned for b128,
                         // bank-stride 20 -> even 8-lanes/bank spread (floor rate)

typedef _Float16 f16;
typedef _Float16 f16x2 __attribute__((ext_vector_type(2)));
typedef _Float16 f16x8 __attribute__((ext_vector_type(8)));
typedef float floatx4 __attribute__((ext_vector_type(4)));

#if __has_builtin(__builtin_amdgcn_exp2f)
#define FAST_EXP2(x) __builtin_amdgcn_exp2f(x)
#else
#define FAST_EXP2(x) exp2f(x)
#endif
#if __has_builtin(__builtin_amdgcn_rcpf)
#define FAST_RCP(x) __builtin_amdgcn_rcpf(x)
#else
#define FAST_RCP(x) (1.0f / (x))
#endif

__global__ __launch_bounds__(BLOCK) void k_proj(
    const float* __restrict__ mol,   // (B, A, 3)
    const float* __restrict__ stds,  // (A)
    const float* __restrict__ dens,  // (A)
    float* __restrict__ out,         // (B, S, S) fp32, pre-zeroed
    int B, int A)
{
    __shared__ f16 sgx[S * LDST];    // Gx^T: [col n][atom k]  (10.0 KB)
    __shared__ f16 sgy[S * LDST];    // (coef*Gy)^T: [row h][atom k]

    const int ks   = blockIdx.x;
    const int b    = blockIdx.y;
    const int tid  = threadIdx.x;
    const int lane = tid & 63;
    const int wav  = tid >> 6;
    const int l15  = lane & 15;
    const int quad = lane >> 4;

    const int per = (A + KSPLIT - 1) / KSPLIT;   // 625
    const int a0 = ks * per;
    const int a1 = min(a0 + per, A);

    floatx4 acc[2][8];
#pragma unroll
    for (int r = 0; r < 2; ++r)
#pragma unroll
        for (int c = 0; c < 8; ++c) acc[r][c] = (floatx4){0.f, 0.f, 0.f, 0.f};

    // staging assignment: thread owns atom pair kp,kp+1 and 8 positions pg+16j
    const int kp = (tid & 15) * 2;
    const int pg = tid >> 4;                     // 0..15

    for (int base = a0; base < a1; base += KB) {
        // per-thread atom params (redundant x16 across threads; L1-broadcast)
        const int aA = base + kp, aB = aA + 1;
        float xA = 0.f, yA = 0.f, kA = 0.f, cA = -100000.f;
        float xB = 0.f, yB = 0.f, kB = 0.f, cB = -100000.f;
        if (aA < a1) {
            xA = mol[((size_t)b * A + aA) * 3 + 0];
            yA = mol[((size_t)b * A + aA) * 3 + 1];
            float v = stds[aA] * stds[aA];
            float rv = FAST_RCP(v);
            kA = -0.72134752044448f * rv;                           // -0.5*log2e/var
            cA = __log2f(dens[aA] * 0.15915494309189535f * rv);     // log2(coef)
        }
        if (aB < a1) {
            xB = mol[((size_t)b * A + aB) * 3 + 0];
            yB = mol[((size_t)b * A + aB) * 3 + 1];
            float v = stds[aB] * stds[aB];
            float rv = FAST_RCP(v);
            kB = -0.72134752044448f * rv;
            cB = __log2f(dens[aB] * 0.15915494309189535f * rv);
        }
        // dead atoms: k=0 -> gx=1 (harmless), c=-1e5 -> gy=0 -> product 0.

        __syncthreads();   // previous chunk's fragment reads complete
#pragma unroll
        for (int j = 0; j < 8; ++j) {
            const int n = pg + 16 * j;
            const float d = (float)n - 63.5f;
            float dxA = d - xA, dxB = d - xB;
            float exA = FAST_EXP2(dxA * dxA * kA);
            float exB = FAST_EXP2(dxB * dxB * kB);
            *(f16x2*)&sgx[n * LDST + kp] = (f16x2){(f16)exA, (f16)exB};
            float dyA = d - yA, dyB = d - yB;
            float eyA = FAST_EXP2(fmaf(dyA * dyA, kA, cA));
            float eyB = FAST_EXP2(fmaf(dyB * dyB, kB, cB));
            *(f16x2*)&sgy[n * LDST + kp] = (f16x2){(f16)eyA, (f16)eyB};
        }
        __syncthreads();   // staging visible

        // A-frag (Gy): A[m = l15][k = quad*8+j]; wave owns tile-rows 2w, 2w+1
        f16x8 afr0 = *(const f16x8*)&sgy[(32 * wav      + l15) * LDST + quad * 8];
        f16x8 afr1 = *(const f16x8*)&sgy[(32 * wav + 16 + l15) * LDST + quad * 8];
#pragma unroll
        for (int c = 0; c < 8; ++c) {
            // B-frag (Gx): B[k = quad*8+j][n = l15]
            f16x8 bfr = *(const f16x8*)&sgx[(16 * c + l15) * LDST + quad * 8];
            acc[0][c] = __builtin_amdgcn_mfma_f32_16x16x32_f16(afr0, bfr, acc[0][c], 0, 0, 0);
            acc[1][c] = __builtin_amdgcn_mfma_f32_16x16x32_f16(afr1, bfr, acc[1][c], 0, 0, 0);
        }
    }

    // epilogue: C/D layout col = l15, row = quad*4 + v (within 16x16 tile)
    const size_t ob = (size_t)b * S * S;
#pragma unroll
    for (int r = 0; r < 2; ++r) {
        const int mbase = 32 * wav + 16 * r + quad * 4;
#pragma unroll
        for (int c = 0; c < 8; ++c) {
            const int col = 16 * c + l15;
#pragma unroll
            for (int v = 0; v < 4; ++v)
                atomicAdd(&out[ob + (size_t)(mbase + v) * S + col], acc[r][c][v]);
        }
    }
}

extern "C" void kernel_launch(void* const* d_in, const int* in_sizes, int n_in,
                              void* d_out, int out_size, void* d_ws, size_t ws_size,
                              hipStream_t stream) {
    const float* mol  = (const float*)d_in[0];
    const float* stds = (const float*)d_in[1];
    const float* dens = (const float*)d_in[2];
    float* out = (float*)d_out;

    const int A = in_sizes[1];             // 20000
    const int B = in_sizes[0] / (A * 3);   // 16

    hipMemsetAsync(d_out, 0, (size_t)out_size * sizeof(float), stream);
    k_proj<<<dim3(KSPLIT, B), dim3(BLOCK), 0, stream>>>(mol, stds, dens, out, B, A);
}

// Round 7
// 107.020 us; speedup vs baseline: 6.3439x; 1.0728x over previous
//
#include <hip/hip_runtime.h>

// Separable projector on f16 matrix cores, v2.
// R6 (64.8us kernel): VALUBusy 24.6%, Occ 18.8% -> stall-bound. Fixes:
//  (a) BLOCK=512, KSPLIT up to 64 -> 3-4 blocks/CU instead of 2 small ones.
//  (b) epilogue = plain float4 stores of per-block partial images into d_ws,
//      merged by k_reduce (replaces 8.4M global fp32 atomics + the memset).
//  (c) k_prep computes per-atom (k = -log2e/2var, c2 = log2(dens/2pi var))
//      once instead of 32x-redundantly per staging thread.
// Fallback to atomic epilogue if ws_size is too small for the partials.

#define S 128
#define KB 32            // atoms per chunk = MFMA K
#define BLOCK 512        // 8 waves; wave w owns output row-tile w (16 rows)
#define LDST 40          // f16 per LDS row: 16B-aligned rows, reads 2-way (free);
                         // writes ~3-way (measured 2.95M cy total in R6 = minor)

typedef _Float16 f16;
typedef _Float16 f16x2 __attribute__((ext_vector_type(2)));
typedef _Float16 f16x8 __attribute__((ext_vector_type(8)));
typedef float floatx4 __attribute__((ext_vector_type(4)));

#if __has_builtin(__builtin_amdgcn_exp2f)
#define FAST_EXP2(x) __builtin_amdgcn_exp2f(x)
#else
#define FAST_EXP2(x) exp2f(x)
#endif
#if __has_builtin(__builtin_amdgcn_rcpf)
#define FAST_RCP(x) __builtin_amdgcn_rcpf(x)
#else
#define FAST_RCP(x) (1.0f / (x))
#endif

// per-atom params, once: k2[a] = -0.5*log2e/var, c2[a] = log2(dens/(2 pi var))
__global__ __launch_bounds__(256) void k_prep(const float* __restrict__ stds,
                                              const float* __restrict__ dens,
                                              float* __restrict__ k2,
                                              float* __restrict__ c2, int A) {
    int a = blockIdx.x * 256 + threadIdx.x;
    if (a >= A) return;
    float v  = stds[a] * stds[a];
    float rv = FAST_RCP(v);
    k2[a] = -0.72134752044448f * rv;
    c2[a] = __log2f(dens[a] * 0.15915494309189535f * rv);
}

__global__ __launch_bounds__(BLOCK) void k_proj(
    const float* __restrict__ mol,   // (B, A, 3)
    const float* __restrict__ k2,
    const float* __restrict__ c2,
    float* __restrict__ dst,         // ws partials (use_ws) or out (atomic path)
    int B, int A, int KS, int use_ws)
{
    __shared__ f16 sgx[S * LDST];    // Gx^T: [col n][atom k]
    __shared__ f16 sgy[S * LDST];    // (coef*Gy)^T: [row h][atom k]

    const int ks   = blockIdx.x;
    const int b    = blockIdx.y;
    const int tid  = threadIdx.x;
    const int lane = tid & 63;
    const int wav  = tid >> 6;       // 0..7 = output row-tile
    const int l15  = lane & 15;
    const int quad = lane >> 4;

    const int per = (A + KS - 1) / KS;
    const int a0 = ks * per;
    const int a1 = min(a0 + per, A);

    floatx4 acc[8];
#pragma unroll
    for (int c = 0; c < 8; ++c) acc[c] = (floatx4){0.f, 0.f, 0.f, 0.f};

    // staging: thread owns atom pair kp,kp+1 and 4 positions pg+32j
    const int kp = (tid & 15) * 2;
    const int pg = tid >> 4;                     // 0..31

    for (int base = a0; base < a1; base += KB) {
        const int aA = base + kp, aB = aA + 1;
        float xA = 0.f, yA = 0.f, kA = 0.f, cA = -100000.f;
        float xB = 0.f, yB = 0.f, kB = 0.f, cB = -100000.f;
        if (aA < a1) {
            xA = mol[((size_t)b * A + aA) * 3 + 0];
            yA = mol[((size_t)b * A + aA) * 3 + 1];
            kA = k2[aA];  cA = c2[aA];
        }
        if (aB < a1) {
            xB = mol[((size_t)b * A + aB) * 3 + 0];
            yB = mol[((size_t)b * A + aB) * 3 + 1];
            kB = k2[aB];  cB = c2[aB];
        }
        // dead atoms: k=0 -> gx=1 (harmless), c=-1e5 -> gy=0 -> product 0.

        __syncthreads();   // previous chunk's fragment reads complete
#pragma unroll
        for (int j = 0; j < 4; ++j) {
            const int n = pg + 32 * j;
            const float d = (float)n - 63.5f;
            float dxA = d - xA, dxB = d - xB;
            float exA = FAST_EXP2(dxA * dxA * kA);
            float exB = FAST_EXP2(dxB * dxB * kB);
            *(f16x2*)&sgx[n * LDST + kp] = (f16x2){(f16)exA, (f16)exB};
            float dyA = d - yA, dyB = d - yB;
            float eyA = FAST_EXP2(fmaf(dyA * dyA, kA, cA));
            float eyB = FAST_EXP2(fmaf(dyB * dyB, kB, cB));
            *(f16x2*)&sgy[n * LDST + kp] = (f16x2){(f16)eyA, (f16)eyB};
        }
        __syncthreads();   // staging visible

        // A-frag (Gy): A[m=l15][k=quad*8+j], wave's row-tile = wav
        f16x8 afr = *(const f16x8*)&sgy[(wav * 16 + l15) * LDST + quad * 8];
#pragma unroll
        for (int c = 0; c < 8; ++c) {
            f16x8 bfr = *(const f16x8*)&sgx[(c * 16 + l15) * LDST + quad * 8];
            acc[c] = __builtin_amdgcn_mfma_f32_16x16x32_f16(afr, bfr, acc[c], 0, 0, 0);
        }
    }

    if (use_ws) {
        // partial image, layout: [flatblk][wav][ct][lane] float4
        float* p = dst + ((size_t)(b * KS + ks)) * (S * S) + wav * 2048;
#pragma unroll
        for (int c = 0; c < 8; ++c)
            *(floatx4*)&p[c * 256 + lane * 4] = acc[c];
    } else {
        const size_t ob = (size_t)b * S * S;
#pragma unroll
        for (int c = 0; c < 8; ++c) {
            const int col = c * 16 + l15;
            const int r0  = wav * 16 + quad * 4;
#pragma unroll
            for (int v = 0; v < 4; ++v)
                atomicAdd(&dst[ob + (size_t)(r0 + v) * S + col], acc[c][v]);
        }
    }
}

// sum KS partial images per batch; writes every output pixel (no memset needed)
__global__ __launch_bounds__(64) void k_reduce(const float* __restrict__ ws,
                                               float* __restrict__ out, int KS) {
    const int ct = blockIdx.x;     // 0..7 col-tile
    const int w  = blockIdx.y;     // 0..7 row-tile
    const int b  = blockIdx.z;
    const int t  = threadIdx.x;    // 0..63

    size_t base = ((size_t)b * KS) * (S * S) + w * 2048 + ct * 256 + t * 4;
    floatx4 s0 = {0.f, 0.f, 0.f, 0.f}, s1 = {0.f, 0.f, 0.f, 0.f};
    for (int s = 0; s < KS; s += 2) {
        s0 += *(const floatx4*)&ws[base + (size_t)s * (S * S)];
        s1 += *(const floatx4*)&ws[base + (size_t)(s + 1) * (S * S)];
    }
    floatx4 sum = s0 + s1;

    const int q = t >> 4, l15 = t & 15;
    const int col = ct * 16 + l15;
    const int r0  = w * 16 + q * 4;
#pragma unroll
    for (int v = 0; v < 4; ++v)
        out[((size_t)b * S + (r0 + v)) * S + col] = sum[v];
}

extern "C" void kernel_launch(void* const* d_in, const int* in_sizes, int n_in,
                              void* d_out, int out_size, void* d_ws, size_t ws_size,
                              hipStream_t stream) {
    const float* mol  = (const float*)d_in[0];
    const float* stds = (const float*)d_in[1];
    const float* dens = (const float*)d_in[2];
    float* out = (float*)d_out;

    const int A = in_sizes[1];             // 20000
    const int B = in_sizes[0] / (A * 3);   // 16

    char* ws = (char*)d_ws;
    float* k2 = (float*)ws;
    float* c2 = (float*)(ws + (size_t)A * 4);
    size_t part_off = (((size_t)A * 8) + 255) & ~(size_t)255;
    float* part = (float*)(ws + part_off);

    const size_t img_bytes = (size_t)S * S * 4;
    int KS, use_ws;
    if (ws_size >= part_off + (size_t)64 * B * img_bytes)      { KS = 64; use_ws = 1; }
    else if (ws_size >= part_off + (size_t)32 * B * img_bytes) { KS = 32; use_ws = 1; }
    else                                                       { KS = 32; use_ws = 0; }

    k_prep<<<(A + 255) / 256, 256, 0, stream>>>(stds, dens, k2, c2, A);

    if (!use_ws)
        hipMemsetAsync(d_out, 0, (size_t)out_size * sizeof(float), stream);

    k_proj<<<dim3(KS, B), dim3(BLOCK), 0, stream>>>(
        mol, k2, c2, use_ws ? part : out, B, A, KS, use_ws);

    if (use_ws)
        k_reduce<<<dim3(8, 8, B), dim3(64), 0, stream>>>(part, out, KS);
}

// Round 8
// 103.867 us; speedup vs baseline: 6.5366x; 1.0304x over previous
//
#include <hip/hip_runtime.h>

// Separable projector on f16 matrix cores, v3.
// Fixed floor: harness re-poisons the 268MB workspace at 6TB/s = ~45us on our
// stream before every replay (R7 top-5: fillBufferAligned 44.8us). Controllable
// R7 part ~62us. R8: KS 64->32 (halves partial-image HBM traffic), LDS
// double-buffer (1 barrier/chunk instead of 2), float2-packed per-atom params.

#define S 128
#define KB 32            // atoms per chunk = MFMA K
#define KSPLIT 32        // K-splits per batch -> 512 blocks, 2/CU, 16 waves/CU
#define BLOCK 512        // 8 waves; wave w owns output row-tile w (16 rows)
#define LDST 40          // f16 per LDS row: rows 16B-aligned; conflicts minor (R6)

typedef _Float16 f16;
typedef _Float16 f16x2 __attribute__((ext_vector_type(2)));
typedef _Float16 f16x8 __attribute__((ext_vector_type(8)));
typedef float floatx4 __attribute__((ext_vector_type(4)));

#if __has_builtin(__builtin_amdgcn_exp2f)
#define FAST_EXP2(x) __builtin_amdgcn_exp2f(x)
#else
#define FAST_EXP2(x) exp2f(x)
#endif
#if __has_builtin(__builtin_amdgcn_rcpf)
#define FAST_RCP(x) __builtin_amdgcn_rcpf(x)
#else
#define FAST_RCP(x) (1.0f / (x))
#endif

// per-atom params once: kc[a] = ( -0.5*log2e/var , log2(dens/(2 pi var)) )
__global__ __launch_bounds__(256) void k_prep(const float* __restrict__ stds,
                                              const float* __restrict__ dens,
                                              float2* __restrict__ kc, int A) {
    int a = blockIdx.x * 256 + threadIdx.x;
    if (a >= A) return;
    float v  = stds[a] * stds[a];
    float rv = FAST_RCP(v);
    kc[a] = make_float2(-0.72134752044448f * rv,
                        __log2f(dens[a] * 0.15915494309189535f * rv));
}

__global__ __launch_bounds__(BLOCK) void k_proj(
    const float* __restrict__ mol,   // (B, A, 3)
    const float2* __restrict__ kc,   // (A) packed params
    float* __restrict__ part,        // (B*KSPLIT, 128*128) partial images
    int B, int A)
{
    __shared__ f16 sgx[2][S * LDST];   // Gx^T: [col n][atom k], double-buffered
    __shared__ f16 sgy[2][S * LDST];   // (coef*Gy)^T: [row h][atom k]

    const int ks   = blockIdx.x;
    const int b    = blockIdx.y;
    const int tid  = threadIdx.x;
    const int lane = tid & 63;
    const int wav  = tid >> 6;       // 0..7 = output row-tile
    const int l15  = lane & 15;
    const int quad = lane >> 4;

    const int per = (A + KSPLIT - 1) / KSPLIT;   // 625
    const int a0 = ks * per;
    const int a1 = min(a0 + per, A);

    floatx4 acc[8];
#pragma unroll
    for (int c = 0; c < 8; ++c) acc[c] = (floatx4){0.f, 0.f, 0.f, 0.f};

    // staging: thread owns atom pair kp,kp+1 and 4 positions pg+32j
    const int kp = (tid & 15) * 2;
    const int pg = tid >> 4;                     // 0..31

    int db = 0;
    for (int base = a0; base < a1; base += KB, db ^= 1) {
        const int aA = base + kp, aB = aA + 1;
        float xA = 0.f, yA = 0.f, kA = 0.f, cA = -100000.f;
        float xB = 0.f, yB = 0.f, kB = 0.f, cB = -100000.f;
        if (aA < a1) {
            xA = mol[((size_t)b * A + aA) * 3 + 0];
            yA = mol[((size_t)b * A + aA) * 3 + 1];
            float2 p = kc[aA];  kA = p.x;  cA = p.y;
        }
        if (aB < a1) {
            xB = mol[((size_t)b * A + aB) * 3 + 0];
            yB = mol[((size_t)b * A + aB) * 3 + 1];
            float2 p = kc[aB];  kB = p.x;  cB = p.y;
        }
        // dead atoms: k=0 -> gx=1 (harmless), c=-1e5 -> gy=0 -> product 0.

#pragma unroll
        for (int j = 0; j < 4; ++j) {
            const int n = pg + 32 * j;
            const float d = (float)n - 63.5f;
            float dxA = d - xA, dxB = d - xB;
            float exA = FAST_EXP2(dxA * dxA * kA);
            float exB = FAST_EXP2(dxB * dxB * kB);
            *(f16x2*)&sgx[db][n * LDST + kp] = (f16x2){(f16)exA, (f16)exB};
            float dyA = d - yA, dyB = d - yB;
            float eyA = FAST_EXP2(fmaf(dyA * dyA, kA, cA));
            float eyB = FAST_EXP2(fmaf(dyB * dyB, kB, cB));
            *(f16x2*)&sgy[db][n * LDST + kp] = (f16x2){(f16)eyA, (f16)eyB};
        }
        __syncthreads();   // staging of buffer db visible; WAR on db is 2 iters
                           // away and fenced by the next barrier + lgkmcnt(0)

        // A-frag (Gy): A[m=l15][k=quad*8+j], wave's row-tile = wav
        f16x8 afr = *(const f16x8*)&sgy[db][(wav * 16 + l15) * LDST + quad * 8];
#pragma unroll
        for (int c = 0; c < 8; ++c) {
            f16x8 bfr = *(const f16x8*)&sgx[db][(c * 16 + l15) * LDST + quad * 8];
            acc[c] = __builtin_amdgcn_mfma_f32_16x16x32_f16(afr, bfr, acc[c], 0, 0, 0);
        }
    }

    // epilogue: fire-and-forget float4 stores of the partial image
    float* p = part + ((size_t)(b * KSPLIT + ks)) * (S * S) + wav * 2048;
#pragma unroll
    for (int c = 0; c < 8; ++c)
        *(floatx4*)&p[c * 256 + lane * 4] = acc[c];
}

// sum KSPLIT partial images per batch; writes every output pixel (no memset)
__global__ __launch_bounds__(64) void k_reduce(const float* __restrict__ ws,
                                               float* __restrict__ out) {
    const int ct = blockIdx.x;     // 0..7 col-tile
    const int w  = blockIdx.y;     // 0..7 row-tile
    const int b  = blockIdx.z;
    const int t  = threadIdx.x;    // 0..63

    size_t base = ((size_t)b * KSPLIT) * (S * S) + w * 2048 + ct * 256 + t * 4;
    floatx4 s0 = {0.f, 0.f, 0.f, 0.f}, s1 = {0.f, 0.f, 0.f, 0.f};
    for (int s = 0; s < KSPLIT; s += 2) {
        s0 += *(const floatx4*)&ws[base + (size_t)s * (S * S)];
        s1 += *(const floatx4*)&ws[base + (size_t)(s + 1) * (S * S)];
    }
    floatx4 sum = s0 + s1;

    // C/D layout within the 16x16 tile: col = t&15, row = (t>>4)*4 + v
    const int q = t >> 4, l15 = t & 15;
    const int col = ct * 16 + l15;
    const int r0  = w * 16 + q * 4;
#pragma unroll
    for (int v = 0; v < 4; ++v)
        out[((size_t)b * S + (r0 + v)) * S + col] = sum[v];
}

extern "C" void kernel_launch(void* const* d_in, const int* in_sizes, int n_in,
                              void* d_out, int out_size, void* d_ws, size_t ws_size,
                              hipStream_t stream) {
    const float* mol  = (const float*)d_in[0];
    const float* stds = (const float*)d_in[1];
    const float* dens = (const float*)d_in[2];
    float* out = (float*)d_out;

    const int A = in_sizes[1];             // 20000
    const int B = in_sizes[0] / (A * 3);   // 16

    char* ws = (char*)d_ws;
    float2* kc = (float2*)ws;
    size_t part_off = (((size_t)A * 8) + 255) & ~(size_t)255;
    float* part = (float*)(ws + part_off);
    // needs part_off + 32*16*64KB = ~33.7 MB; ws is 268 MB.

    k_prep<<<(A + 255) / 256, 256, 0, stream>>>(stds, dens, kc, A);
    k_proj<<<dim3(KSPLIT, B), dim3(BLOCK), 0, stream>>>(mol, kc, part, B, A);
    k_reduce<<<dim3(8, 8, B), dim3(64), 0, stream>>>(part, out);
}